// Round 5
// baseline (299.543 us; speedup 1.0000x reference)
//
#include <hip/hip_runtime.h>
#include <hip/hip_bf16.h>
#include <math.h>

#define Bc 4
#define Lc 1024
#define Dc 768
#define Hc 12
#define Ec 24
#define Mc 4
#define Pc 552
#define EMBc 768
#define NLc 97
#define Rc (Bc*Pc)      // 2208
#define KSPL 24         // bilinear: 12 k-blocks x 2 splits of i

typedef __attribute__((ext_vector_type(4))) float f32x4;
typedef __attribute__((ext_vector_type(8))) short short8;

static __device__ __forceinline__ unsigned short f2bf(float x){
  unsigned int u = __float_as_uint(x);
  unsigned int r = u + 0x7fffu + ((u >> 16) & 1u);   // RNE
  return (unsigned short)(r >> 16);
}
static __device__ __forceinline__ unsigned short f2bf_hw(float x){
  __hip_bfloat16 h = __float2bfloat16(x);            // hw RNE cvt
  return __builtin_bit_cast(unsigned short, h);
}

// ---------------- K0: fused weight prep ----------------
__global__ __launch_bounds__(256) void k_prep(const float* __restrict__ bilW, unsigned short* __restrict__ Wbf,
                                              const float* __restrict__ seq, unsigned short* __restrict__ seqt,
                                              const float* __restrict__ W_q, unsigned short* __restrict__ Wq_t,
                                              const float* __restrict__ W_k, unsigned short* __restrict__ Wk_t,
                                              const float* __restrict__ headW, unsigned short* __restrict__ headW_t,
                                              const float* __restrict__ tailW, unsigned short* __restrict__ tailW_t){
  int bx = blockIdx.x;
  if (bx < 1536){
    const float* Ws = bilW + (size_t)bx*32*NLc;
    unsigned short* o = Wbf + (size_t)bx*4480;
    for (int idx = threadIdx.x; idx < 112*32; idx += 256){
      int n = idx % 112, kk = idx / 112;
      float v = (n < NLc) ? Ws[(size_t)kk*NLc + n] : 0.f;
      o[n*40 + kk] = f2bf(v);
    }
    return;
  }
  bx -= 1536;
  const float* src; unsigned short* dst; int rows, cols, r0, c0;
  if (bx < 768){           // seq [1024x768] x4 -> seqt [768x1024]
    int z = bx / 192, rem = bx % 192;
    src = seq + (size_t)z*Lc*Dc; dst = seqt + (size_t)z*Dc*Lc;
    rows = Lc; cols = Dc; r0 = (rem % 16)*64; c0 = (rem / 16)*64;
  } else if (bx < 768+144){
    int rem = bx - 768;
    src = W_q; dst = Wq_t; rows = Dc; cols = Dc; r0 = (rem % 12)*64; c0 = (rem / 12)*64;
  } else if (bx < 768+288){
    int rem = bx - (768+144);
    src = W_k; dst = Wk_t; rows = Dc; cols = Dc; r0 = (rem % 12)*64; c0 = (rem / 12)*64;
  } else if (bx < 768+288+288){
    int rem = bx - (768+288);
    src = headW; dst = headW_t; rows = 2*Dc; cols = Dc; r0 = (rem % 24)*64; c0 = (rem / 24)*64;
  } else {
    int rem = bx - (768+288+288);
    src = tailW; dst = tailW_t; rows = 2*Dc; cols = Dc; r0 = (rem % 24)*64; c0 = (rem / 24)*64;
  }
  __shared__ float t[64][65];
  #pragma unroll
  for (int q = 0; q < 16; q++){
    int idx = q*256 + threadIdx.x;
    int rr = idx >> 6, cc = idx & 63;
    t[rr][cc] = src[(size_t)(r0+rr)*cols + c0+cc];
  }
  __syncthreads();
  #pragma unroll
  for (int q = 0; q < 16; q++){
    int idx = q*256 + threadIdx.x;
    int cc = idx >> 6, rr = idx & 63;
    dst[(size_t)(c0+cc)*rows + r0+rr] = f2bf(t[rr][cc]);
  }
}

// ---------------- K1: ent_att + mention gather (fused) ----------------
__global__ __launch_bounds__(256) void k_ent_att(const float* __restrict__ att,
                                                 const int* __restrict__ mpos,
                                                 const float* __restrict__ seq,
                                                 float* __restrict__ ent_att,
                                                 float* __restrict__ ment,
                                                 unsigned short* __restrict__ ment_bf){
  int blk = blockIdx.x;             // (b*E+e)*H + h, 1152 blocks
  int h  = blk % Hc;
  int be = blk / Hc;
  int b  = be / Ec;
  int p0 = mpos[be*Mc+0]+1, p1 = mpos[be*Mc+1]+1;
  int p2 = mpos[be*Mc+2]+1, p3 = mpos[be*Mc+3]+1;
  const float* ab = att + ((size_t)b*Hc + h)*Lc*Lc;
  const float* a0 = ab + (size_t)p0*Lc;
  const float* a1 = ab + (size_t)p1*Lc;
  const float* a2 = ab + (size_t)p2*Lc;
  const float* a3 = ab + (size_t)p3*Lc;
  float* o = ent_att + (size_t)blk*Lc;
  for (int l = threadIdx.x; l < Lc; l += 256)
    o[l] = 0.25f*(a0[l]+a1[l]+a2[l]+a3[l]);
  int gidx = blk*256 + threadIdx.x;
  int d = gidx % Dc;
  int bem = gidx / Dc;
  int bb = bem / (Ec*Mc);
  int pos = mpos[bem] + 1;
  float v = seq[((size_t)bb*Lc + pos)*Dc + d];
  ment[gidx] = v;
  ment_bf[gidx] = f2bf(v);
}

// ---------------- K2: ht_att -> bf16, XCD-aligned batches ----------------
__global__ __launch_bounds__(256) void k_ht_att(const float* __restrict__ ent_att,
                                                const int* __restrict__ hts,
                                                unsigned short* __restrict__ htbf){
  int b = blockIdx.x & 3;
  int p = blockIdx.x >> 2;
  int r = b*Pc + p;
  int hi = hts[r*2+0], ti = hts[r*2+1];
  const float* eh = ent_att + (size_t)(b*Ec+hi)*Hc*Lc;
  const float* et = ent_att + (size_t)(b*Ec+ti)*Hc*Lc;
  __shared__ float raw[Lc];
  __shared__ float wsum[4];
  int l4 = threadIdx.x*4;
  float4 s4 = {0.f,0.f,0.f,0.f};
  #pragma unroll
  for (int h = 0; h < Hc; h++){
    float4 e1 = *(const float4*)&eh[h*Lc + l4];
    float4 e2 = *(const float4*)&et[h*Lc + l4];
    s4.x = fmaf(e1.x,e2.x,s4.x); s4.y = fmaf(e1.y,e2.y,s4.y);
    s4.z = fmaf(e1.z,e2.z,s4.z); s4.w = fmaf(e1.w,e2.w,s4.w);
  }
  s4.x *= (1.0f/Hc); s4.y *= (1.0f/Hc); s4.z *= (1.0f/Hc); s4.w *= (1.0f/Hc);
  *(float4*)&raw[l4] = s4;
  float lsum = s4.x+s4.y+s4.z+s4.w;
  for (int off = 32; off; off >>= 1) lsum += __shfl_down(lsum, off);
  if ((threadIdx.x & 63) == 0) wsum[threadIdx.x>>6] = lsum;
  __syncthreads();
  float inv = 1.0f/(wsum[0]+wsum[1]+wsum[2]+wsum[3] + 1e-5f);
  unsigned short* o = htbf + (size_t)r*Lc;
  float4 rv = *(const float4*)&raw[l4];
  unsigned short ov[4] = { f2bf(rv.x*inv), f2bf(rv.y*inv), f2bf(rv.z*inv), f2bf(rv.w*inv) };
  *(ushort2*)&o[l4]   = *(ushort2*)&ov[0];
  *(ushort2*)&o[l4+2] = *(ushort2*)&ov[2];
}

// ---------------- K3 (MFMA): rs_bf = htbf @ seqt^T, M-tile 64 ----------------
__global__ __launch_bounds__(256) void k_rs_mfma(const unsigned short* __restrict__ htbf,
                                                 const unsigned short* __restrict__ seqt,
                                                 unsigned short* __restrict__ rs_bf){
  int b = blockIdx.z;
  const unsigned short* A = htbf + (size_t)b*Pc*Lc;
  const unsigned short* Wt = seqt + (size_t)b*Dc*Lc;
  unsigned short* C = rs_bf + (size_t)b*Pc*Dc;
  int lane = threadIdx.x & 63, wid = threadIdx.x >> 6;
  int row16 = lane & 15, oct = lane >> 4;
  int rbase = blockIdx.x*64 + wid*16;
  int r0 = rbase + row16; if (r0 > Pc-1) r0 = Pc-1;
  const unsigned short* a0p = A + (size_t)r0*Lc + oct*8;
  const unsigned short* wp  = Wt + (size_t)(blockIdx.y*64 + row16)*Lc + oct*8;
  f32x4 acc[4];
  #pragma unroll
  for (int n = 0; n < 4; n++) acc[n] = (f32x4){0.f,0.f,0.f,0.f};
  #pragma unroll 4
  for (int kc = 0; kc < Lc; kc += 32){
    short8 a0 = *(const short8*)(a0p + kc);
    #pragma unroll
    for (int n = 0; n < 4; n++){
      short8 bv = *(const short8*)(wp + (size_t)n*16*Lc + kc);
      acc[n] = __builtin_amdgcn_mfma_f32_16x16x32_bf16(a0, bv, acc[n], 0, 0, 0);
    }
  }
  #pragma unroll
  for (int n = 0; n < 4; n++)
    #pragma unroll
    for (int j = 0; j < 4; j++){
      int r = rbase + oct*4 + j;
      if (r < Pc){
        int col = blockIdx.y*64 + n*16 + row16;
        C[(size_t)r*Dc + col] = f2bf(acc[n][j]);
      }
    }
}

// ---------------- K4: generic MFMA GEMM, M-tile 64, 2 jobs per launch ----------------
struct GemmJob {
  const unsigned short* A1; const unsigned short* A2; int K2;
  const unsigned short* Wt; const float* bias; float* C; int M; int do_tanh;
};

__global__ __launch_bounds__(256) void k_gemm(GemmJob j0, GemmJob j1, int nx0){
  GemmJob j = (blockIdx.x < nx0) ? j0 : j1;
  int mbx = (blockIdx.x < nx0) ? blockIdx.x : blockIdx.x - nx0;
  const int Ktot = Dc + j.K2;
  int lane = threadIdx.x & 63, wid = threadIdx.x >> 6;
  int row16 = lane & 15, oct = lane >> 4;
  int rbase = mbx*64 + wid*16;
  int r0 = rbase + row16; if (r0 > j.M-1) r0 = j.M-1;
  const unsigned short* a0p = j.A1 + (size_t)r0*Dc + oct*8;
  const unsigned short* wp  = j.Wt + (size_t)(blockIdx.y*64 + row16)*Ktot + oct*8;
  f32x4 acc[4];
  #pragma unroll
  for (int n = 0; n < 4; n++) acc[n] = (f32x4){0.f,0.f,0.f,0.f};
  #pragma unroll 4
  for (int kc = 0; kc < Dc; kc += 32){
    short8 a0 = *(const short8*)(a0p + kc);
    #pragma unroll
    for (int n = 0; n < 4; n++){
      short8 bv = *(const short8*)(wp + (size_t)n*16*Ktot + kc);
      acc[n] = __builtin_amdgcn_mfma_f32_16x16x32_bf16(a0, bv, acc[n], 0, 0, 0);
    }
  }
  if (j.K2 > 0){
    const unsigned short* b0p = j.A2 + (size_t)r0*Dc + oct*8;
    const unsigned short* wp2 = wp + Dc;
    #pragma unroll 4
    for (int kc = 0; kc < Dc; kc += 32){
      short8 a0 = *(const short8*)(b0p + kc);
      #pragma unroll
      for (int n = 0; n < 4; n++){
        short8 bv = *(const short8*)(wp2 + (size_t)n*16*Ktot + kc);
        acc[n] = __builtin_amdgcn_mfma_f32_16x16x32_bf16(a0, bv, acc[n], 0, 0, 0);
      }
    }
  }
  #pragma unroll
  for (int n = 0; n < 4; n++)
    #pragma unroll
    for (int j4 = 0; j4 < 4; j4++){
      int r = rbase + oct*4 + j4;
      if (r < j.M){
        int col = blockIdx.y*64 + n*16 + row16;
        float v = acc[n][j4];
        if (j.bias) v += j.bias[col];
        if (j.do_tanh) v = tanhf(v);
        j.C[(size_t)r*Dc + col] = v;
      }
    }
}

// ---------------- K6: pool (softmax over M=4, both sides) ----------------
__global__ __launch_bounds__(256) void k_pool(const float* __restrict__ kment,
                                              const float* __restrict__ ment,
                                              const float* __restrict__ q_c,
                                              const int* __restrict__ hts,
                                              unsigned short* __restrict__ h_bf,
                                              unsigned short* __restrict__ t_bf){
  int r = blockIdx.x;
  int b = r / Pc;
  __shared__ float q[Dc];
  __shared__ float sred[16];
  __shared__ float sw[Mc];
  for (int d = threadIdx.x; d < Dc; d += 256) q[d] = q_c[(size_t)r*Dc + d];
  __syncthreads();
  const float invs = 0.03608439182435161f;  // 1/sqrt(768)
  for (int side = 0; side < 2; side++){
    int e = hts[r*2+side];
    const float* kb = kment + (size_t)(b*Ec+e)*Mc*Dc;
    const float* mb = ment  + (size_t)(b*Ec+e)*Mc*Dc;
    float part[Mc] = {0.f,0.f,0.f,0.f};
    for (int d = threadIdx.x; d < Dc; d += 256){
      float qv = q[d];
      #pragma unroll
      for (int m = 0; m < Mc; m++) part[m] = fmaf(kb[m*Dc+d], qv, part[m]);
    }
    #pragma unroll
    for (int m = 0; m < Mc; m++)
      for (int off = 32; off; off >>= 1) part[m] += __shfl_down(part[m], off);
    if ((threadIdx.x & 63) == 0){
      int w = threadIdx.x >> 6;
      #pragma unroll
      for (int m = 0; m < Mc; m++) sred[w*4+m] = part[m];
    }
    __syncthreads();
    if (threadIdx.x == 0){
      float sc[Mc]; float mx = -1e30f;
      for (int m = 0; m < Mc; m++){
        sc[m] = (sred[m]+sred[4+m]+sred[8+m]+sred[12+m])*invs;
        mx = fmaxf(mx, sc[m]);
      }
      float ssum = 0.f;
      for (int m = 0; m < Mc; m++){ sc[m] = expf(sc[m]-mx); ssum += sc[m]; }
      float isum = 1.0f/ssum;
      for (int m = 0; m < Mc; m++) sw[m] = sc[m]*isum;
    }
    __syncthreads();
    float w0 = sw[0], w1 = sw[1], w2 = sw[2], w3 = sw[3];
    unsigned short* o = (side ? t_bf : h_bf) + (size_t)r*Dc;
    for (int d = threadIdx.x; d < 768; d += 256)
      o[d] = f2bf(w0*mb[d] + w1*mb[Dc+d] + w2*mb[2*Dc+d] + w3*mb[3*Dc+d]);
    __syncthreads();
  }
}

// ---------------- K8: MFMA bilinear, M-tile 64, paired chunks ----------------
// grid = mb(36) x kb(24); wave = 16 rows x 7 n-tiles; one barrier per 2 chunks
__global__ __launch_bounds__(256) void k_bilinear_mfma(
    const float* __restrict__ hs, const float* __restrict__ ts,
    const unsigned short* __restrict__ Wbf,
    float* __restrict__ partial)
{
  int mb = blockIdx.x / KSPL;
  int kb = blockIdx.x % KSPL;
  int k  = kb >> 1;             // EMB block 0..11
  int i0 = (kb & 1) * 32;       // i sub-range (32 wide)

  int tid  = threadIdx.x;
  int lane = tid & 63;
  int wid  = tid >> 6;
  int row16 = lane & 15;
  int oct   = lane >> 4;

  int rbase = mb*64 + wid*16;

  __shared__ __align__(16) unsigned short Wlds[2][8960];  // 2 chunks per buffer

  float4 tsr[2][2];   // [jhalf][q]
  float4 hsr[8];      // hs[r][k*64+i0 .. +31]
  {
    int r = rbase + row16; if (r > Rc-1) r = Rc-1;
    const float* tp = ts + (size_t)r*EMBc + k*64;
    tsr[0][0] = *(const float4*)(tp + oct*8);
    tsr[0][1] = *(const float4*)(tp + oct*8 + 4);
    tsr[1][0] = *(const float4*)(tp + 32 + oct*8);
    tsr[1][1] = *(const float4*)(tp + 32 + oct*8 + 4);
    const float* hp = hs + (size_t)r*EMBc + k*64 + i0;
    #pragma unroll
    for (int q = 0; q < 8; q++) hsr[q] = *(const float4*)(hp + q*4);
  }

  const char* wsrc = (const char*)(Wbf + ((size_t)(k*128 + i0*2))*4480);

  // stage pair 0 -> buf 0 (17920 B = 1120 x 16B)
  #pragma unroll
  for (int rr = 0; rr < 5; rr++){
    int u = tid + rr*256;
    if (u < 1120)
      __builtin_amdgcn_global_load_lds(
        (const __attribute__((address_space(1))) unsigned int*)(wsrc + (size_t)u*16),
        (__attribute__((address_space(3))) unsigned int*)((char*)&Wlds[0][0] + u*16),
        16, 0, 0);
  }

  f32x4 acc[7];
  #pragma unroll
  for (int n = 0; n < 7; n++) acc[n] = (f32x4){0.f,0.f,0.f,0.f};

  __syncthreads();   // pair 0 staged

  for (int cp = 0; cp < 32; cp++){
    int cur = cp & 1;
    if (cp < 31){
      const char* nsrc = wsrc + (size_t)(cp+1)*17920;
      #pragma unroll
      for (int rr = 0; rr < 5; rr++){
        int u = tid + rr*256;
        if (u < 1120)
          __builtin_amdgcn_global_load_lds(
            (const __attribute__((address_space(1))) unsigned int*)(nsrc + (size_t)u*16),
            (__attribute__((address_space(3))) unsigned int*)((char*)&Wlds[cur^1][0] + u*16),
            16, 0, 0);
      }
    }
    #pragma unroll
    for (int half = 0; half < 2; half++){
      int c = cp*2 + half;
      const int ci = c >> 1, cj = c & 1;
      float hv = ((const float*)&hsr[ci>>2])[ci&3];
      float4 t0 = tsr[cj][0];
      float4 t1 = tsr[cj][1];
      short8 af;
      af[0] = (short)f2bf_hw(hv*t0.x);
      af[1] = (short)f2bf_hw(hv*t0.y);
      af[2] = (short)f2bf_hw(hv*t0.z);
      af[3] = (short)f2bf_hw(hv*t0.w);
      af[4] = (short)f2bf_hw(hv*t1.x);
      af[5] = (short)f2bf_hw(hv*t1.y);
      af[6] = (short)f2bf_hw(hv*t1.z);
      af[7] = (short)f2bf_hw(hv*t1.w);
      #pragma unroll
      for (int n = 0; n < 7; n++){
        short8 bfr = *(const short8*)&Wlds[cur][half*4480 + (n*16 + row16)*40 + oct*8];
        acc[n] = __builtin_amdgcn_mfma_f32_16x16x32_bf16(af, bfr, acc[n], 0, 0, 0);
      }
    }
    __syncthreads();   // buf[cur] reads done; buf[cur^1] staged
  }

  float* pk = partial + (size_t)kb*Rc*NLc;
  #pragma unroll
  for (int n = 0; n < 7; n++){
    #pragma unroll
    for (int j = 0; j < 4; j++){
      int r = rbase + oct*4 + j;
      int col = n*16 + row16;
      if (r < Rc && col < NLc)
        pk[(size_t)r*NLc + col] = acc[n][j];
    }
  }
}

// ---------------- K9: sum partials + bias ----------------
__global__ __launch_bounds__(256) void k_reduce(const float* __restrict__ partial,
                                                const float* __restrict__ bilb,
                                                float* __restrict__ out){
  int idx = blockIdx.x*256 + threadIdx.x;
  if (idx >= Rc*NLc) return;
  int n = idx % NLc;
  float s = bilb[n];
  #pragma unroll
  for (int ks = 0; ks < KSPL; ks++) s += partial[(size_t)ks*Rc*NLc + idx];
  out[idx] = s;
}

extern "C" void kernel_launch(void* const* d_in, const int* in_sizes, int n_in,
                              void* d_out, int out_size, void* d_ws, size_t ws_size,
                              hipStream_t stream){
  const float* seq   = (const float*)d_in[0];
  const float* att   = (const float*)d_in[1];
  const float* W_q   = (const float*)d_in[2];
  const float* W_k   = (const float*)d_in[3];
  const float* headW = (const float*)d_in[4];
  const float* headb = (const float*)d_in[5];
  const float* tailW = (const float*)d_in[6];
  const float* tailb = (const float*)d_in[7];
  const float* bilW  = (const float*)d_in[8];
  const float* bilb  = (const float*)d_in[9];
  const int*   mpos  = (const int*)d_in[10];
  const int*   hts   = (const int*)d_in[11];
  float* out = (float*)d_out;

  float* ws = (float*)d_ws;
  float* ent_att = ws;                                      // 1,179,648 f
  float* q_c     = ws + 1179648;                            // 1,695,744 f
  float* kment   = q_c + 1695744;                           //   294,912 f
  float* ment    = kment + 294912;                          //   294,912 f
  unsigned short* seqt    = (unsigned short*)(ment + 294912);   // 3,145,728 u16
  unsigned short* htbf    = seqt + 3145728;                     // 2,260,992
  unsigned short* rs_bf   = htbf + 2260992;                     // 1,695,744
  unsigned short* ment_bf = rs_bf + 1695744;                    //   294,912
  unsigned short* h_bf    = ment_bf + 294912;                   // 1,695,744
  unsigned short* t_bf    = h_bf + 1695744;                     // 1,695,744
  unsigned short* Wq_t    = t_bf + 1695744;                     //   589,824
  unsigned short* Wk_t    = Wq_t + 589824;                      //   589,824
  unsigned short* headW_t = Wk_t + 589824;                      // 1,179,648
  unsigned short* tailW_t = headW_t + 1179648;                  // 1,179,648
  float* hsb = (float*)(tailW_t + 1179648);                 // = ws + 10,629,120
  float* tsb = hsb + 1695744;
  unsigned short* Wbf = (unsigned short*)(tsb + 1695744);   // 6,881,280 u16
  float* partial = ws;   // 24*2208*97 = 5,140,224 f, overlaps dead prefix region

  k_prep   <<<3168, 256, 0, stream>>>(bilW, Wbf, seq, seqt, W_q, Wq_t, W_k, Wk_t,
                                      headW, headW_t, tailW, tailW_t);
  k_ent_att<<<Bc*Ec*Hc, 256, 0, stream>>>(att, mpos, seq, ent_att, ment, ment_bf);
  k_ht_att <<<Rc, 256, 0, stream>>>(ent_att, hts, htbf);
  k_rs_mfma<<<dim3(9,12,4), 256, 0, stream>>>(htbf, seqt, rs_bf);
  {
    GemmJob jq  = { rs_bf,   nullptr, 0, Wq_t, nullptr, q_c,   Rc,        0 };
    GemmJob jk  = { ment_bf, nullptr, 0, Wk_t, nullptr, kment, Bc*Ec*Mc,  0 };
    k_gemm <<<dim3(41,12), 256, 0, stream>>>(jq, jk, 35);
  }
  k_pool   <<<Rc, 256, 0, stream>>>(kment, ment, q_c, hts, h_bf, t_bf);
  {
    GemmJob jh = { h_bf, rs_bf, Dc, headW_t, headb, hsb, Rc, 1 };
    GemmJob jt = { t_bf, rs_bf, Dc, tailW_t, tailb, tsb, Rc, 1 };
    k_gemm <<<dim3(70,12), 256, 0, stream>>>(jh, jt, 35);
  }
  k_bilinear_mfma<<<36*KSPL, 256, 0, stream>>>(hsb, tsb, Wbf, partial);
  k_reduce <<<(Rc*NLc+255)/256, 256, 0, stream>>>(partial, bilb, out);
}

// Round 6
// 195.483 us; speedup vs baseline: 1.5323x; 1.5323x over previous
//
#include <hip/hip_runtime.h>
#include <hip/hip_bf16.h>
#include <math.h>

#define Bc 4
#define Lc 1024
#define Dc 768
#define Hc 12
#define Ec 24
#define Mc 4
#define Pc 552
#define EMBc 768
#define NLc 97
#define Rc (Bc*Pc)      // 2208
#define KSPL 24         // bilinear: 12 k-blocks x 2 splits of i
#define HT_ABS (35*32*512)   // htbf flin per-batch stride (shorts), 35 mt (552 rows + pad)

typedef __attribute__((ext_vector_type(4))) float f32x4;
typedef __attribute__((ext_vector_type(8))) short short8;
typedef __attribute__((ext_vector_type(4))) unsigned short us4;

static __device__ __forceinline__ unsigned short f2bf(float x){
  unsigned int u = __float_as_uint(x);
  unsigned int r = u + 0x7fffu + ((u >> 16) & 1u);   // RNE
  return (unsigned short)(r >> 16);
}
static __device__ __forceinline__ unsigned short f2bf_hw(float x){
  __hip_bfloat16 h = __float2bfloat16(x);
  return __builtin_bit_cast(unsigned short, h);
}
// flin index: row r, k-index kk, KT = K/32 chunks
static __device__ __forceinline__ size_t flin_off(int r, int kk, int KT){
  return ((size_t)(r>>4)*KT + (kk>>5))*512 + (size_t)((((kk&31)>>3)*16 + (r&15))*8) + (kk&7);
}

// ---------------- K0: weight prep (bilinear chunks + flin converts) ----------------
__global__ __launch_bounds__(256) void k_prep(const float* __restrict__ bilW, unsigned short* __restrict__ Wbf,
                                              const float* __restrict__ seq, unsigned short* __restrict__ seqf,
                                              const float* __restrict__ W_q, unsigned short* __restrict__ Wq_f,
                                              const float* __restrict__ W_k, unsigned short* __restrict__ Wk_f,
                                              const float* __restrict__ headW, unsigned short* __restrict__ headW_f,
                                              const float* __restrict__ tailW, unsigned short* __restrict__ tailW_f){
  int bx = blockIdx.x;
  int tid = threadIdx.x;
  if (bx < 1536){
    const float* Ws = bilW + (size_t)bx*32*NLc;
    unsigned short* o = Wbf + (size_t)bx*4480;
    for (int idx = tid; idx < 112*32; idx += 256){
      int n = idx % 112, kk = idx / 112;
      float v = (n < NLc) ? Ws[(size_t)kk*NLc + n] : 0.f;
      o[n*40 + kk] = f2bf(v);
    }
    return;
  }
  bx -= 1536;
  const float* src; unsigned short* dst; int tk, tn, KTW;
  if (bx < 768){                     // seq [1024x768] x4 -> flin KTW=32
    int z = bx / 192, rem = bx % 192;
    src = seq + (size_t)z*Lc*Dc; dst = seqf + (size_t)z*(Dc/16)*(Lc/32)*512;
    tk = rem % 16; tn = rem / 16; KTW = 32;
  } else if (bx < 768+144){
    int rem = bx - 768;
    src = W_q; dst = Wq_f; tk = rem % 12; tn = rem / 12; KTW = 24;
  } else if (bx < 768+288){
    int rem = bx - (768+144);
    src = W_k; dst = Wk_f; tk = rem % 12; tn = rem / 12; KTW = 24;
  } else if (bx < 768+288+288){
    int rem = bx - (768+288);
    src = headW; dst = headW_f; tk = rem % 24; tn = rem / 24; KTW = 48;
  } else {
    int rem = bx - (768+288+288);
    src = tailW; dst = tailW_f; tk = rem % 24; tn = rem / 24; KTW = 48;
  }
  int r0 = tk*64, c0 = tn*64;       // r0 along K, c0 along N(=768)
  __shared__ float t[64][65];
  #pragma unroll
  for (int q8 = 0; q8 < 16; q8++){
    int idx = q8*256 + tid;
    int rr = idx >> 6, cc = idx & 63;
    t[rr][cc] = src[(size_t)(r0+rr)*768 + c0+cc];
  }
  __syncthreads();
  #pragma unroll
  for (int q8 = 0; q8 < 16; q8++){
    int idx = q8*256 + tid;
    int li = idx & 511, sub = idx >> 9;
    int nt_l = sub >> 1, kt_l = sub & 1;
    int lane = li >> 3, e = li & 7;
    int kl = kt_l*32 + (lane>>4)*8 + e;
    int nl = nt_l*16 + (lane&15);
    dst[ ((size_t)(c0/16 + nt_l)*KTW + (r0/32 + kt_l))*512 + li ] = f2bf(t[kl][nl]);
  }
}

// ---------------- K1: ent_att + mention gather (ment fp32 + flin bf16) ----------------
__global__ __launch_bounds__(256) void k_ent_att(const float* __restrict__ att,
                                                 const int* __restrict__ mpos,
                                                 const float* __restrict__ seq,
                                                 float* __restrict__ ent_att,
                                                 float* __restrict__ ment,
                                                 unsigned short* __restrict__ ment_bf){
  int blk = blockIdx.x;             // (b*E+e)*H + h, 1152 blocks
  int h  = blk % Hc;
  int be = blk / Hc;
  int b  = be / Ec;
  int p0 = mpos[be*Mc+0]+1, p1 = mpos[be*Mc+1]+1;
  int p2 = mpos[be*Mc+2]+1, p3 = mpos[be*Mc+3]+1;
  const float* ab = att + ((size_t)b*Hc + h)*Lc*Lc;
  const float* a0 = ab + (size_t)p0*Lc;
  const float* a1 = ab + (size_t)p1*Lc;
  const float* a2 = ab + (size_t)p2*Lc;
  const float* a3 = ab + (size_t)p3*Lc;
  float* o = ent_att + (size_t)blk*Lc;
  for (int l = threadIdx.x; l < Lc; l += 256)
    o[l] = 0.25f*(a0[l]+a1[l]+a2[l]+a3[l]);
  int gidx = blk*256 + threadIdx.x;           // over B*E*M*D
  int d = gidx % Dc;
  int bem = gidx / Dc;
  int bb = bem / (Ec*Mc);
  int pos = mpos[bem] + 1;
  float v = seq[((size_t)bb*Lc + pos)*Dc + d];
  ment[gidx] = v;
  ment_bf[flin_off(bem, d, 24)] = f2bf(v);
}

// ---------------- K2: ht_att -> bf16 flin (with zero pad rows 552..559) ----------------
__global__ __launch_bounds__(256) void k_ht_att(const float* __restrict__ ent_att,
                                                const int* __restrict__ hts,
                                                unsigned short* __restrict__ htbf){
  int b = blockIdx.x & 3;
  int p = blockIdx.x >> 2;          // 0..559
  unsigned short* o = htbf + (size_t)b*HT_ABS;
  int l4 = threadIdx.x*4;
  if (p >= Pc){                     // zero-pad tile rows
    us4 z4 = {0,0,0,0};
    *(us4*)(o + flin_off(p, l4, 32)) = z4;
    return;
  }
  int r = b*Pc + p;
  int hi = hts[r*2+0], ti = hts[r*2+1];
  const float* eh = ent_att + (size_t)(b*Ec+hi)*Hc*Lc;
  const float* et = ent_att + (size_t)(b*Ec+ti)*Hc*Lc;
  __shared__ float raw[Lc];
  __shared__ float wsum[4];
  float4 s4 = {0.f,0.f,0.f,0.f};
  #pragma unroll
  for (int h = 0; h < Hc; h++){
    float4 e1 = *(const float4*)&eh[h*Lc + l4];
    float4 e2 = *(const float4*)&et[h*Lc + l4];
    s4.x = fmaf(e1.x,e2.x,s4.x); s4.y = fmaf(e1.y,e2.y,s4.y);
    s4.z = fmaf(e1.z,e2.z,s4.z); s4.w = fmaf(e1.w,e2.w,s4.w);
  }
  s4.x *= (1.0f/Hc); s4.y *= (1.0f/Hc); s4.z *= (1.0f/Hc); s4.w *= (1.0f/Hc);
  *(float4*)&raw[l4] = s4;
  float lsum = s4.x+s4.y+s4.z+s4.w;
  for (int off = 32; off; off >>= 1) lsum += __shfl_down(lsum, off);
  if ((threadIdx.x & 63) == 0) wsum[threadIdx.x>>6] = lsum;
  __syncthreads();
  float inv = 1.0f/(wsum[0]+wsum[1]+wsum[2]+wsum[3] + 1e-5f);
  float4 rv = *(const float4*)&raw[l4];
  us4 v4;
  v4[0] = f2bf(rv.x*inv); v4[1] = f2bf(rv.y*inv);
  v4[2] = f2bf(rv.z*inv); v4[3] = f2bf(rv.w*inv);
  *(us4*)(o + flin_off(p, l4, 32)) = v4;
}

// ---------------- K4: flin MFMA GEMM (no LDS, fully coalesced frag loads) ----------------
struct FJob {
  const unsigned short* A1; const unsigned short* A2;
  const unsigned short* W;  const float* bias; void* C;
  int M; int mtmax; size_t Abs; size_t Wbs; int rowsPerBatch;
};

// CT: 0 = fp32 (+bias if set), 1 = fp32 + bias + tanh, 2 = bf16 flin (KTC=24)
template<int KT1, int KT2, int CT>
__global__ __launch_bounds__(256) void k_fgemm(FJob j0, FJob j1, int nx0){
  FJob j = (blockIdx.x < nx0) ? j0 : j1;
  int mbx = (blockIdx.x < nx0) ? blockIdx.x : blockIdx.x - nx0;
  const int KTW = KT1 + KT2;
  int z = blockIdx.z;
  int lane = threadIdx.x & 63, wid = threadIdx.x >> 6;
  int row16 = lane & 15, oct = lane >> 4;
  int rb = mbx*64 + wid*16;
  int mt = rb >> 4; if (mt >= j.mtmax) mt = j.mtmax - 1;
  const unsigned short* ap = j.A1 + (size_t)z*j.Abs + (size_t)mt*KT1*512 + lane*8;
  const unsigned short* wb = j.W  + (size_t)z*j.Wbs + (size_t)(blockIdx.y*4)*KTW*512 + lane*8;
  f32x4 acc[4];
  #pragma unroll
  for (int n = 0; n < 4; n++) acc[n] = (f32x4){0.f,0.f,0.f,0.f};
  #pragma unroll 4
  for (int kt = 0; kt < KT1; kt++){
    short8 a = *(const short8*)(ap + (size_t)kt*512);
    #pragma unroll
    for (int n = 0; n < 4; n++){
      short8 bv = *(const short8*)(wb + (size_t)(n*KTW + kt)*512);
      acc[n] = __builtin_amdgcn_mfma_f32_16x16x32_bf16(a, bv, acc[n], 0, 0, 0);
    }
  }
  if (KT2 > 0){
    const unsigned short* ap2 = j.A2 + (size_t)mt*KT2*512 + lane*8;
    #pragma unroll 4
    for (int kt = 0; kt < KT2; kt++){
      short8 a = *(const short8*)(ap2 + (size_t)kt*512);
      #pragma unroll
      for (int n = 0; n < 4; n++){
        short8 bv = *(const short8*)(wb + (size_t)(n*KTW + KT1 + kt)*512);
        acc[n] = __builtin_amdgcn_mfma_f32_16x16x32_bf16(a, bv, acc[n], 0, 0, 0);
      }
    }
  }
  int colb = blockIdx.y*64;
  #pragma unroll
  for (int n = 0; n < 4; n++)
    #pragma unroll
    for (int jj = 0; jj < 4; jj++){
      int r = rb + oct*4 + jj;
      if (r < j.M){
        int col = colb + n*16 + row16;
        float v = acc[n][jj];
        if (CT <= 1 && j.bias) v += j.bias[col];
        if (CT == 1) v = tanhf(v);
        int rg = z*j.rowsPerBatch + r;
        if (CT == 2){
          ((unsigned short*)j.C)[flin_off(rg, col, 24)] = f2bf(v);
        } else {
          ((float*)j.C)[(size_t)rg*768 + col] = v;
        }
      }
    }
}

// ---------------- K6: pool (softmax over M=4, both sides) -> flin bf16 ----------------
__global__ __launch_bounds__(256) void k_pool(const float* __restrict__ kment,
                                              const float* __restrict__ ment,
                                              const float* __restrict__ q_c,
                                              const int* __restrict__ hts,
                                              unsigned short* __restrict__ h_bf,
                                              unsigned short* __restrict__ t_bf){
  int r = blockIdx.x;
  int b = r / Pc;
  __shared__ float q[Dc];
  __shared__ float sred[16];
  __shared__ float sw[Mc];
  for (int d = threadIdx.x; d < Dc; d += 256) q[d] = q_c[(size_t)r*Dc + d];
  __syncthreads();
  const float invs = 0.03608439182435161f;  // 1/sqrt(768)
  for (int side = 0; side < 2; side++){
    int e = hts[r*2+side];
    const float* kb = kment + (size_t)(b*Ec+e)*Mc*Dc;
    const float* mb = ment  + (size_t)(b*Ec+e)*Mc*Dc;
    float part[Mc] = {0.f,0.f,0.f,0.f};
    for (int d = threadIdx.x; d < Dc; d += 256){
      float qv = q[d];
      #pragma unroll
      for (int m = 0; m < Mc; m++) part[m] = fmaf(kb[m*Dc+d], qv, part[m]);
    }
    #pragma unroll
    for (int m = 0; m < Mc; m++)
      for (int off = 32; off; off >>= 1) part[m] += __shfl_down(part[m], off);
    if ((threadIdx.x & 63) == 0){
      int w = threadIdx.x >> 6;
      #pragma unroll
      for (int m = 0; m < Mc; m++) sred[w*4+m] = part[m];
    }
    __syncthreads();
    if (threadIdx.x == 0){
      float sc[Mc]; float mx = -1e30f;
      for (int m = 0; m < Mc; m++){
        sc[m] = (sred[m]+sred[4+m]+sred[8+m]+sred[12+m])*invs;
        mx = fmaxf(mx, sc[m]);
      }
      float ssum = 0.f;
      for (int m = 0; m < Mc; m++){ sc[m] = expf(sc[m]-mx); ssum += sc[m]; }
      float isum = 1.0f/ssum;
      for (int m = 0; m < Mc; m++) sw[m] = sc[m]*isum;
    }
    __syncthreads();
    float w0 = sw[0], w1 = sw[1], w2 = sw[2], w3 = sw[3];
    unsigned short* o = side ? t_bf : h_bf;
    for (int d = threadIdx.x; d < Dc; d += 256)
      o[flin_off(r, d, 24)] = f2bf(w0*mb[d] + w1*mb[Dc+d] + w2*mb[2*Dc+d] + w3*mb[3*Dc+d]);
    __syncthreads();
  }
}

// ---------------- K8: MFMA bilinear (round-5 structure) ----------------
__global__ __launch_bounds__(256) void k_bilinear_mfma(
    const float* __restrict__ hs, const float* __restrict__ ts,
    const unsigned short* __restrict__ Wbf,
    float* __restrict__ partial)
{
  int mb = blockIdx.x / KSPL;
  int kb = blockIdx.x % KSPL;
  int k  = kb >> 1;
  int i0 = (kb & 1) * 32;

  int tid  = threadIdx.x;
  int lane = tid & 63;
  int wid  = tid >> 6;
  int row16 = lane & 15;
  int oct   = lane >> 4;

  int rbase = mb*64 + wid*16;

  __shared__ __align__(16) unsigned short Wlds[2][8960];

  float4 tsr[2][2];
  float4 hsr[8];
  {
    int r = rbase + row16; if (r > Rc-1) r = Rc-1;
    const float* tp = ts + (size_t)r*EMBc + k*64;
    tsr[0][0] = *(const float4*)(tp + oct*8);
    tsr[0][1] = *(const float4*)(tp + oct*8 + 4);
    tsr[1][0] = *(const float4*)(tp + 32 + oct*8);
    tsr[1][1] = *(const float4*)(tp + 32 + oct*8 + 4);
    const float* hp = hs + (size_t)r*EMBc + k*64 + i0;
    #pragma unroll
    for (int q = 0; q < 8; q++) hsr[q] = *(const float4*)(hp + q*4);
  }

  const char* wsrc = (const char*)(Wbf + ((size_t)(k*128 + i0*2))*4480);

  #pragma unroll
  for (int rr = 0; rr < 5; rr++){
    int u = tid + rr*256;
    if (u < 1120)
      __builtin_amdgcn_global_load_lds(
        (const __attribute__((address_space(1))) unsigned int*)(wsrc + (size_t)u*16),
        (__attribute__((address_space(3))) unsigned int*)((char*)&Wlds[0][0] + u*16),
        16, 0, 0);
  }

  f32x4 acc[7];
  #pragma unroll
  for (int n = 0; n < 7; n++) acc[n] = (f32x4){0.f,0.f,0.f,0.f};

  __syncthreads();

  for (int cp = 0; cp < 32; cp++){
    int cur = cp & 1;
    if (cp < 31){
      const char* nsrc = wsrc + (size_t)(cp+1)*17920;
      #pragma unroll
      for (int rr = 0; rr < 5; rr++){
        int u = tid + rr*256;
        if (u < 1120)
          __builtin_amdgcn_global_load_lds(
            (const __attribute__((address_space(1))) unsigned int*)(nsrc + (size_t)u*16),
            (__attribute__((address_space(3))) unsigned int*)((char*)&Wlds[cur^1][0] + u*16),
            16, 0, 0);
      }
    }
    #pragma unroll
    for (int half = 0; half < 2; half++){
      int c = cp*2 + half;
      const int ci = c >> 1, cj = c & 1;
      float hv = ((const float*)&hsr[ci>>2])[ci&3];
      float4 t0 = tsr[cj][0];
      float4 t1 = tsr[cj][1];
      short8 af;
      af[0] = (short)f2bf_hw(hv*t0.x);
      af[1] = (short)f2bf_hw(hv*t0.y);
      af[2] = (short)f2bf_hw(hv*t0.z);
      af[3] = (short)f2bf_hw(hv*t0.w);
      af[4] = (short)f2bf_hw(hv*t1.x);
      af[5] = (short)f2bf_hw(hv*t1.y);
      af[6] = (short)f2bf_hw(hv*t1.z);
      af[7] = (short)f2bf_hw(hv*t1.w);
      #pragma unroll
      for (int n = 0; n < 7; n++){
        short8 bfr = *(const short8*)&Wlds[cur][half*4480 + (n*16 + row16)*40 + oct*8];
        acc[n] = __builtin_amdgcn_mfma_f32_16x16x32_bf16(af, bfr, acc[n], 0, 0, 0);
      }
    }
    __syncthreads();
  }

  float* pk = partial + (size_t)kb*Rc*NLc;
  #pragma unroll
  for (int n = 0; n < 7; n++){
    #pragma unroll
    for (int j = 0; j < 4; j++){
      int r = rbase + oct*4 + j;
      int col = n*16 + row16;
      if (r < Rc && col < NLc)
        pk[(size_t)r*NLc + col] = acc[n][j];
    }
  }
}

// ---------------- K9: sum partials + bias ----------------
__global__ __launch_bounds__(256) void k_reduce(const float* __restrict__ partial,
                                                const float* __restrict__ bilb,
                                                float* __restrict__ out){
  int idx = blockIdx.x*256 + threadIdx.x;
  if (idx >= Rc*NLc) return;
  int n = idx % NLc;
  float s = bilb[n];
  #pragma unroll
  for (int ks = 0; ks < KSPL; ks++) s += partial[(size_t)ks*Rc*NLc + idx];
  out[idx] = s;
}

extern "C" void kernel_launch(void* const* d_in, const int* in_sizes, int n_in,
                              void* d_out, int out_size, void* d_ws, size_t ws_size,
                              hipStream_t stream){
  const float* seq   = (const float*)d_in[0];
  const float* att   = (const float*)d_in[1];
  const float* W_q   = (const float*)d_in[2];
  const float* W_k   = (const float*)d_in[3];
  const float* headW = (const float*)d_in[4];
  const float* headb = (const float*)d_in[5];
  const float* tailW = (const float*)d_in[6];
  const float* tailb = (const float*)d_in[7];
  const float* bilW  = (const float*)d_in[8];
  const float* bilb  = (const float*)d_in[9];
  const int*   mpos  = (const int*)d_in[10];
  const int*   hts   = (const int*)d_in[11];
  float* out = (float*)d_out;

  float* ws = (float*)d_ws;
  float* ent_att = ws;                                      // 1,179,648 f
  float* q_c     = ws + 1179648;                            // 1,695,744 f
  float* kment   = q_c + 1695744;                           //   294,912 f
  float* ment    = kment + 294912;                          //   294,912 f
  unsigned short* seqf    = (unsigned short*)(ment + 294912);   // 3,145,728 sh
  unsigned short* htbf    = seqf + 3145728;                     // 2,293,760 sh (4*HT_ABS)
  unsigned short* rs_bf   = htbf + 4*HT_ABS;                    // 1,695,744 sh
  unsigned short* ment_bf = rs_bf + 1695744;                    //   294,912 sh
  unsigned short* h_bf    = ment_bf + 294912;                   // 1,695,744 sh
  unsigned short* t_bf    = h_bf + 1695744;                     // 1,695,744 sh
  unsigned short* Wq_f    = t_bf + 1695744;                     //   589,824 sh
  unsigned short* Wk_f    = Wq_f + 589824;                      //   589,824 sh
  unsigned short* headW_f = Wk_f + 589824;                      // 1,179,648 sh
  unsigned short* tailW_f = headW_f + 1179648;                  // 1,179,648 sh
  float* hsb = (float*)(tailW_f + 1179648);
  float* tsb = hsb + 1695744;
  unsigned short* Wbf = (unsigned short*)(tsb + 1695744);   // 6,881,280 sh
  float* partial = ws;   // 24*2208*97 = 5,140,224 f, overlaps dead prefix region

  k_prep   <<<3168, 256, 0, stream>>>(bilW, Wbf, seq, seqf, W_q, Wq_f, W_k, Wk_f,
                                      headW, headW_f, tailW, tailW_f);
  k_ent_att<<<Bc*Ec*Hc, 256, 0, stream>>>(att, mpos, seq, ent_att, ment, ment_bf);
  k_ht_att <<<4*560, 256, 0, stream>>>(ent_att, hts, htbf);
  {
    FJob jrs = { htbf, nullptr, seqf, nullptr, rs_bf, Pc, 35,
                 (size_t)HT_ABS, (size_t)(48*32*512), Pc };
    k_fgemm<32,0,2><<<dim3(9,12,4), 256, 0, stream>>>(jrs, jrs, 9);
  }
  {
    FJob jq = { rs_bf,   nullptr, Wq_f, nullptr, q_c,   Rc,       138, 0, 0, 0 };
    FJob jk = { ment_bf, nullptr, Wk_f, nullptr, kment, Bc*Ec*Mc,  24, 0, 0, 0 };
    k_fgemm<24,0,0><<<dim3(41,12), 256, 0, stream>>>(jq, jk, 35);
  }
  k_pool   <<<Rc, 256, 0, stream>>>(kment, ment, q_c, hts, h_bf, t_bf);
  {
    FJob jh = { h_bf, rs_bf, headW_f, headb, hsb, Rc, 138, 0, 0, 0 };
    FJob jt = { t_bf, rs_bf, tailW_f, tailb, tsb, Rc, 138, 0, 0, 0 };
    k_fgemm<24,24,1><<<dim3(70,12), 256, 0, stream>>>(jh, jt, 35);
  }
  k_bilinear_mfma<<<36*KSPL, 256, 0, stream>>>(hsb, tsb, Wbf, partial);
  k_reduce <<<(Rc*NLc+255)/256, 256, 0, stream>>>(partial, bilb, out);
}

// Round 7
// 180.405 us; speedup vs baseline: 1.6604x; 1.0836x over previous
//
#include <hip/hip_runtime.h>
#include <hip/hip_bf16.h>
#include <math.h>

#define Bc 4
#define Lc 1024
#define Dc 768
#define Hc 12
#define Ec 24
#define Mc 4
#define Pc 552
#define EMBc 768
#define NLc 97
#define Rc (Bc*Pc)      // 2208
#define KSPL 24         // bilinear: 12 k-blocks x 2 splits of i
#define HT_ABS (35*32*512)   // htbf flin per-batch stride (shorts)

typedef __attribute__((ext_vector_type(4))) float f32x4;
typedef __attribute__((ext_vector_type(8))) short short8;
typedef __attribute__((ext_vector_type(4))) unsigned short us4;
typedef _Float16 f16x8 __attribute__((ext_vector_type(8)));

static __device__ __forceinline__ unsigned short f2bf(float x){
  unsigned int u = __float_as_uint(x);
  unsigned int r = u + 0x7fffu + ((u >> 16) & 1u);   // RNE
  return (unsigned short)(r >> 16);
}
static __device__ __forceinline__ unsigned short f2h(float x){
  _Float16 h = (_Float16)x;
  return __builtin_bit_cast(unsigned short, h);
}
// flin index: row r, k-index kk, KT = K/32 chunks
static __device__ __forceinline__ size_t flin_off(int r, int kk, int KT){
  return ((size_t)(r>>4)*KT + (kk>>5))*512 + (size_t)((((kk&31)>>3)*16 + (r&15))*8) + (kk&7);
}

// ---------------- K0: weight prep (bilinear fp16 chunks + flin converts) ----------------
__global__ __launch_bounds__(256) void k_prep(const float* __restrict__ bilW, unsigned short* __restrict__ Wbf,
                                              const float* __restrict__ seq, unsigned short* __restrict__ seqf,
                                              const float* __restrict__ W_q, unsigned short* __restrict__ Wq_f,
                                              const float* __restrict__ W_k, unsigned short* __restrict__ Wk_f,
                                              const float* __restrict__ headW, unsigned short* __restrict__ headW_f,
                                              const float* __restrict__ tailW, unsigned short* __restrict__ tailW_f){
  int bx = blockIdx.x;
  int tid = threadIdx.x;
  if (bx < 1536){
    const float* Ws = bilW + (size_t)bx*32*NLc;
    unsigned short* o = Wbf + (size_t)bx*4480;
    for (int idx = tid; idx < 112*32; idx += 256){
      int n = idx % 112, kk = idx / 112;
      float v = (n < NLc) ? Ws[(size_t)kk*NLc + n] : 0.f;
      o[n*40 + kk] = f2h(v);
    }
    return;
  }
  bx -= 1536;
  const float* src; unsigned short* dst; int tk, tn, KTW;
  if (bx < 768){                     // seq [1024x768] x4 -> flin KTW=32
    int z = bx / 192, rem = bx % 192;
    src = seq + (size_t)z*Lc*Dc; dst = seqf + (size_t)z*(Dc/16)*(Lc/32)*512;
    tk = rem % 16; tn = rem / 16; KTW = 32;
  } else if (bx < 768+144){
    int rem = bx - 768;
    src = W_q; dst = Wq_f; tk = rem % 12; tn = rem / 12; KTW = 24;
  } else if (bx < 768+288){
    int rem = bx - (768+144);
    src = W_k; dst = Wk_f; tk = rem % 12; tn = rem / 12; KTW = 24;
  } else if (bx < 768+288+288){
    int rem = bx - (768+288);
    src = headW; dst = headW_f; tk = rem % 24; tn = rem / 24; KTW = 48;
  } else {
    int rem = bx - (768+288+288);
    src = tailW; dst = tailW_f; tk = rem % 24; tn = rem / 24; KTW = 48;
  }
  int r0 = tk*64, c0 = tn*64;       // r0 along K, c0 along N(=768)
  __shared__ float t[64][65];
  #pragma unroll
  for (int q8 = 0; q8 < 16; q8++){
    int idx = q8*256 + tid;
    int rr = idx >> 6, cc = idx & 63;
    t[rr][cc] = src[(size_t)(r0+rr)*768 + c0+cc];
  }
  __syncthreads();
  #pragma unroll
  for (int q8 = 0; q8 < 16; q8++){
    int idx = q8*256 + tid;
    int li = idx & 511, sub = idx >> 9;
    int nt_l = sub >> 1, kt_l = sub & 1;
    int lane = li >> 3, e = li & 7;
    int kl = kt_l*32 + (lane>>4)*8 + e;
    int nl = nt_l*16 + (lane&15);
    dst[ ((size_t)(c0/16 + nt_l)*KTW + (r0/32 + kt_l))*512 + li ] = f2bf(t[kl][nl]);
  }
}

// ---------------- K1: ent_att + mention gather ----------------
__global__ __launch_bounds__(256) void k_ent_att(const float* __restrict__ att,
                                                 const int* __restrict__ mpos,
                                                 const float* __restrict__ seq,
                                                 float* __restrict__ ent_att,
                                                 float* __restrict__ ment,
                                                 unsigned short* __restrict__ ment_bf){
  int blk = blockIdx.x;             // (b*E+e)*H + h, 1152 blocks
  int h  = blk % Hc;
  int be = blk / Hc;
  int b  = be / Ec;
  int p0 = mpos[be*Mc+0]+1, p1 = mpos[be*Mc+1]+1;
  int p2 = mpos[be*Mc+2]+1, p3 = mpos[be*Mc+3]+1;
  const float* ab = att + ((size_t)b*Hc + h)*Lc*Lc;
  const float* a0 = ab + (size_t)p0*Lc;
  const float* a1 = ab + (size_t)p1*Lc;
  const float* a2 = ab + (size_t)p2*Lc;
  const float* a3 = ab + (size_t)p3*Lc;
  float* o = ent_att + (size_t)blk*Lc;
  for (int l = threadIdx.x; l < Lc; l += 256)
    o[l] = 0.25f*(a0[l]+a1[l]+a2[l]+a3[l]);
  int gidx = blk*256 + threadIdx.x;           // over B*E*M*D
  int d = gidx % Dc;
  int bem = gidx / Dc;
  int bb = bem / (Ec*Mc);
  int pos = mpos[bem] + 1;
  float v = seq[((size_t)bb*Lc + pos)*Dc + d];
  ment[gidx] = v;
  ment_bf[flin_off(bem, d, 24)] = f2bf(v);
}

// ---------------- K2: ht_att -> bf16 flin (zero pad rows 552..559) ----------------
__global__ __launch_bounds__(256) void k_ht_att(const float* __restrict__ ent_att,
                                                const int* __restrict__ hts,
                                                unsigned short* __restrict__ htbf){
  int b = blockIdx.x & 3;
  int p = blockIdx.x >> 2;          // 0..559
  unsigned short* o = htbf + (size_t)b*HT_ABS;
  int l4 = threadIdx.x*4;
  if (p >= Pc){
    us4 z4 = {0,0,0,0};
    *(us4*)(o + flin_off(p, l4, 32)) = z4;
    return;
  }
  int r = b*Pc + p;
  int hi = hts[r*2+0], ti = hts[r*2+1];
  const float* eh = ent_att + (size_t)(b*Ec+hi)*Hc*Lc;
  const float* et = ent_att + (size_t)(b*Ec+ti)*Hc*Lc;
  __shared__ float raw[Lc];
  __shared__ float wsum[4];
  float4 s4 = {0.f,0.f,0.f,0.f};
  #pragma unroll
  for (int h = 0; h < Hc; h++){
    float4 e1 = *(const float4*)&eh[h*Lc + l4];
    float4 e2 = *(const float4*)&et[h*Lc + l4];
    s4.x = fmaf(e1.x,e2.x,s4.x); s4.y = fmaf(e1.y,e2.y,s4.y);
    s4.z = fmaf(e1.z,e2.z,s4.z); s4.w = fmaf(e1.w,e2.w,s4.w);
  }
  s4.x *= (1.0f/Hc); s4.y *= (1.0f/Hc); s4.z *= (1.0f/Hc); s4.w *= (1.0f/Hc);
  *(float4*)&raw[l4] = s4;
  float lsum = s4.x+s4.y+s4.z+s4.w;
  for (int off = 32; off; off >>= 1) lsum += __shfl_down(lsum, off);
  if ((threadIdx.x & 63) == 0) wsum[threadIdx.x>>6] = lsum;
  __syncthreads();
  float inv = 1.0f/(wsum[0]+wsum[1]+wsum[2]+wsum[3] + 1e-5f);
  float4 rv = *(const float4*)&raw[l4];
  us4 v4;
  v4[0] = f2bf(rv.x*inv); v4[1] = f2bf(rv.y*inv);
  v4[2] = f2bf(rv.z*inv); v4[3] = f2bf(rv.w*inv);
  *(us4*)(o + flin_off(p, l4, 32)) = v4;
}

// ---------------- K4: flin MFMA GEMM, 2 m-frags/wave (32 rows) ----------------
struct FJob {
  const unsigned short* A1; const unsigned short* A2;
  const unsigned short* W;  const float* bias; void* C;
  int M; int mtmax; size_t Abs; size_t Wbs; int rowsPerBatch;
};

// CT: 0 = fp32 (+bias), 1 = fp32+bias+tanh -> fp16 row-major, 2 = bf16 flin (KTC=24)
template<int KT1, int KT2, int CT>
__global__ __launch_bounds__(256) void k_fgemm(FJob j0, FJob j1, int nx0){
  FJob j = (blockIdx.x < nx0) ? j0 : j1;
  int mbx = (blockIdx.x < nx0) ? blockIdx.x : blockIdx.x - nx0;
  const int KTW = KT1 + KT2;
  int z = blockIdx.z;
  int lane = threadIdx.x & 63, wid = threadIdx.x >> 6;
  int row16 = lane & 15, oct = lane >> 4;
  int rb = mbx*128 + wid*32;
  int mt0 = rb >> 4;       if (mt0 >= j.mtmax) mt0 = j.mtmax - 1;
  int mt1 = (rb >> 4) + 1; if (mt1 >= j.mtmax) mt1 = j.mtmax - 1;
  const unsigned short* ap0 = j.A1 + (size_t)z*j.Abs + (size_t)mt0*KT1*512 + lane*8;
  const unsigned short* ap1 = j.A1 + (size_t)z*j.Abs + (size_t)mt1*KT1*512 + lane*8;
  const unsigned short* wb = j.W  + (size_t)z*j.Wbs + (size_t)(blockIdx.y*4)*KTW*512 + lane*8;
  f32x4 acc[2][4];
  #pragma unroll
  for (int m = 0; m < 2; m++)
    #pragma unroll
    for (int n = 0; n < 4; n++) acc[m][n] = (f32x4){0.f,0.f,0.f,0.f};
  #pragma unroll 4
  for (int kt = 0; kt < KT1; kt++){
    short8 a0 = *(const short8*)(ap0 + (size_t)kt*512);
    short8 a1 = *(const short8*)(ap1 + (size_t)kt*512);
    #pragma unroll
    for (int n = 0; n < 4; n++){
      short8 bv = *(const short8*)(wb + (size_t)(n*KTW + kt)*512);
      acc[0][n] = __builtin_amdgcn_mfma_f32_16x16x32_bf16(a0, bv, acc[0][n], 0, 0, 0);
      acc[1][n] = __builtin_amdgcn_mfma_f32_16x16x32_bf16(a1, bv, acc[1][n], 0, 0, 0);
    }
  }
  if (KT2 > 0){
    const unsigned short* b0p = j.A2 + (size_t)mt0*KT2*512 + lane*8;
    const unsigned short* b1p = j.A2 + (size_t)mt1*KT2*512 + lane*8;
    #pragma unroll 4
    for (int kt = 0; kt < KT2; kt++){
      short8 a0 = *(const short8*)(b0p + (size_t)kt*512);
      short8 a1 = *(const short8*)(b1p + (size_t)kt*512);
      #pragma unroll
      for (int n = 0; n < 4; n++){
        short8 bv = *(const short8*)(wb + (size_t)(n*KTW + KT1 + kt)*512);
        acc[0][n] = __builtin_amdgcn_mfma_f32_16x16x32_bf16(a0, bv, acc[0][n], 0, 0, 0);
        acc[1][n] = __builtin_amdgcn_mfma_f32_16x16x32_bf16(a1, bv, acc[1][n], 0, 0, 0);
      }
    }
  }
  int colb = blockIdx.y*64;
  #pragma unroll
  for (int m = 0; m < 2; m++)
    #pragma unroll
    for (int n = 0; n < 4; n++)
      #pragma unroll
      for (int jj = 0; jj < 4; jj++){
        int r = rb + m*16 + oct*4 + jj;
        if (r < j.M){
          int col = colb + n*16 + row16;
          float v = acc[m][n][jj];
          if (CT <= 1 && j.bias) v += j.bias[col];
          int rg = z*j.rowsPerBatch + r;
          if (CT == 2){
            ((unsigned short*)j.C)[flin_off(rg, col, 24)] = f2bf(v);
          } else if (CT == 1){
            ((unsigned short*)j.C)[(size_t)rg*768 + col] = f2h(tanhf(v));
          } else {
            ((float*)j.C)[(size_t)rg*768 + col] = v;
          }
        }
      }
}

// ---------------- K6: pool (softmax over M=4, both sides) -> flin bf16 ----------------
__global__ __launch_bounds__(256) void k_pool(const float* __restrict__ kment,
                                              const float* __restrict__ ment,
                                              const float* __restrict__ q_c,
                                              const int* __restrict__ hts,
                                              unsigned short* __restrict__ h_bf,
                                              unsigned short* __restrict__ t_bf){
  int r = blockIdx.x;
  int b = r / Pc;
  __shared__ float q[Dc];
  __shared__ float sred[16];
  __shared__ float sw[Mc];
  for (int d = threadIdx.x; d < Dc; d += 256) q[d] = q_c[(size_t)r*Dc + d];
  __syncthreads();
  const float invs = 0.03608439182435161f;  // 1/sqrt(768)
  for (int side = 0; side < 2; side++){
    int e = hts[r*2+side];
    const float* kb = kment + (size_t)(b*Ec+e)*Mc*Dc;
    const float* mb = ment  + (size_t)(b*Ec+e)*Mc*Dc;
    float part[Mc] = {0.f,0.f,0.f,0.f};
    for (int d = threadIdx.x; d < Dc; d += 256){
      float qv = q[d];
      #pragma unroll
      for (int m = 0; m < Mc; m++) part[m] = fmaf(kb[m*Dc+d], qv, part[m]);
    }
    #pragma unroll
    for (int m = 0; m < Mc; m++)
      for (int off = 32; off; off >>= 1) part[m] += __shfl_down(part[m], off);
    if ((threadIdx.x & 63) == 0){
      int w = threadIdx.x >> 6;
      #pragma unroll
      for (int m = 0; m < Mc; m++) sred[w*4+m] = part[m];
    }
    __syncthreads();
    if (threadIdx.x == 0){
      float sc[Mc]; float mx = -1e30f;
      for (int m = 0; m < Mc; m++){
        sc[m] = (sred[m]+sred[4+m]+sred[8+m]+sred[12+m])*invs;
        mx = fmaxf(mx, sc[m]);
      }
      float ssum = 0.f;
      for (int m = 0; m < Mc; m++){ sc[m] = expf(sc[m]-mx); ssum += sc[m]; }
      float isum = 1.0f/ssum;
      for (int m = 0; m < Mc; m++) sw[m] = sc[m]*isum;
    }
    __syncthreads();
    float w0 = sw[0], w1 = sw[1], w2 = sw[2], w3 = sw[3];
    unsigned short* o = side ? t_bf : h_bf;
    for (int d = threadIdx.x; d < Dc; d += 256)
      o[flin_off(r, d, 24)] = f2bf(w0*mb[d] + w1*mb[Dc+d] + w2*mb[2*Dc+d] + w3*mb[3*Dc+d]);
    __syncthreads();
  }
}

// ---------------- K8: MFMA bilinear fp16, 2 m-frags/wave, full unroll ----------------
// grid = mb(18) x kb(24); block 4 waves x 32 rows = 128 rows
__global__ __launch_bounds__(256) void k_bilinear_mfma(
    const unsigned short* __restrict__ hs16, const unsigned short* __restrict__ ts16,
    const unsigned short* __restrict__ Wbf,
    float* __restrict__ partial)
{
  int mb = blockIdx.x / KSPL;
  int kb = blockIdx.x % KSPL;
  int k  = kb >> 1;
  int i0 = (kb & 1) * 32;

  int tid  = threadIdx.x;
  int lane = tid & 63;
  int wid  = tid >> 6;
  int row16 = lane & 15;
  int oct   = lane >> 4;

  int rbase = mb*128 + wid*32;

  __shared__ __align__(16) unsigned short Wlds[2][8960];

  f16x8 tsh[2][2];  // [m][jhalf]
  f16x8 hsh[2][4];  // [m][q], i = q*8 + e
  #pragma unroll
  for (int m = 0; m < 2; m++){
    int r = rbase + m*16 + row16; if (r > Rc-1) r = Rc-1;
    const unsigned short* tp = ts16 + (size_t)r*EMBc + k*64;
    tsh[m][0] = __builtin_bit_cast(f16x8, *(const short8*)(tp + oct*8));
    tsh[m][1] = __builtin_bit_cast(f16x8, *(const short8*)(tp + 32 + oct*8));
    const unsigned short* hp = hs16 + (size_t)r*EMBc + k*64 + i0;
    #pragma unroll
    for (int q = 0; q < 4; q++)
      hsh[m][q] = __builtin_bit_cast(f16x8, *(const short8*)(hp + q*8));
  }

  const char* wsrc = (const char*)(Wbf + ((size_t)(k*128 + i0*2))*4480);

  #pragma unroll
  for (int rr = 0; rr < 5; rr++){
    int u = tid + rr*256;
    if (u < 1120)
      __builtin_amdgcn_global_load_lds(
        (const __attribute__((address_space(1))) unsigned int*)(wsrc + (size_t)u*16),
        (__attribute__((address_space(3))) unsigned int*)((char*)&Wlds[0][0] + u*16),
        16, 0, 0);
  }

  f32x4 acc[2][7];
  #pragma unroll
  for (int m = 0; m < 2; m++)
    #pragma unroll
    for (int n = 0; n < 7; n++) acc[m][n] = (f32x4){0.f,0.f,0.f,0.f};

  __syncthreads();   // pair 0 staged

  #pragma unroll
  for (int cp = 0; cp < 32; cp++){
    int cur = cp & 1;
    if (cp < 31){
      const char* nsrc = wsrc + (size_t)(cp+1)*17920;
      #pragma unroll
      for (int rr = 0; rr < 5; rr++){
        int u = tid + rr*256;
        if (u < 1120)
          __builtin_amdgcn_global_load_lds(
            (const __attribute__((address_space(1))) unsigned int*)(nsrc + (size_t)u*16),
            (__attribute__((address_space(3))) unsigned int*)((char*)&Wlds[cur^1][0] + u*16),
            16, 0, 0);
      }
    }
    #pragma unroll
    for (int half = 0; half < 2; half++){
      f16x8 af[2];
      #pragma unroll
      for (int m = 0; m < 2; m++){
        _Float16 hv = hsh[m][cp>>3][cp&7];       // static after full unroll
        f16x8 hvb = {hv,hv,hv,hv,hv,hv,hv,hv};
        af[m] = tsh[m][half] * hvb;              // 4x v_pk_mul_f16
      }
      #pragma unroll
      for (int n = 0; n < 7; n++){
        f16x8 bfr = __builtin_bit_cast(f16x8,
            *(const short8*)&Wlds[cur][half*4480 + (n*16 + row16)*40 + oct*8]);
        acc[0][n] = __builtin_amdgcn_mfma_f32_16x16x32_f16(af[0], bfr, acc[0][n], 0, 0, 0);
        acc[1][n] = __builtin_amdgcn_mfma_f32_16x16x32_f16(af[1], bfr, acc[1][n], 0, 0, 0);
      }
    }
    __syncthreads();
  }

  float* pk = partial + (size_t)kb*Rc*NLc;
  #pragma unroll
  for (int m = 0; m < 2; m++){
    #pragma unroll
    for (int n = 0; n < 7; n++){
      #pragma unroll
      for (int j = 0; j < 4; j++){
        int r = rbase + m*16 + oct*4 + j;
        int col = n*16 + row16;
        if (r < Rc && col < NLc)
          pk[(size_t)r*NLc + col] = acc[m][n][j];
      }
    }
  }
}

// ---------------- K9: sum partials + bias ----------------
__global__ __launch_bounds__(256) void k_reduce(const float* __restrict__ partial,
                                                const float* __restrict__ bilb,
                                                float* __restrict__ out){
  int idx = blockIdx.x*256 + threadIdx.x;
  if (idx >= Rc*NLc) return;
  int n = idx % NLc;
  float s = bilb[n];
  #pragma unroll
  for (int ks = 0; ks < KSPL; ks++) s += partial[(size_t)ks*Rc*NLc + idx];
  out[idx] = s;
}

extern "C" void kernel_launch(void* const* d_in, const int* in_sizes, int n_in,
                              void* d_out, int out_size, void* d_ws, size_t ws_size,
                              hipStream_t stream){
  const float* seq   = (const float*)d_in[0];
  const float* att   = (const float*)d_in[1];
  const float* W_q   = (const float*)d_in[2];
  const float* W_k   = (const float*)d_in[3];
  const float* headW = (const float*)d_in[4];
  const float* headb = (const float*)d_in[5];
  const float* tailW = (const float*)d_in[6];
  const float* tailb = (const float*)d_in[7];
  const float* bilW  = (const float*)d_in[8];
  const float* bilb  = (const float*)d_in[9];
  const int*   mpos  = (const int*)d_in[10];
  const int*   hts   = (const int*)d_in[11];
  float* out = (float*)d_out;

  float* ws = (float*)d_ws;
  float* ent_att = ws;                                      // 1,179,648 f
  float* q_c     = ws + 1179648;                            // 1,695,744 f
  float* kment   = q_c + 1695744;                           //   294,912 f
  float* ment    = kment + 294912;                          //   294,912 f
  unsigned short* seqf    = (unsigned short*)(ment + 294912);   // 3,145,728 sh
  unsigned short* htbf    = seqf + 3145728;                     // 2,293,760 sh
  unsigned short* rs_bf   = htbf + 4*HT_ABS;                    // 1,695,744 sh
  unsigned short* ment_bf = rs_bf + 1695744;                    //   294,912 sh
  unsigned short* h_bf    = ment_bf + 294912;                   // 1,695,744 sh
  unsigned short* t_bf    = h_bf + 1695744;                     // 1,695,744 sh
  unsigned short* Wq_f    = t_bf + 1695744;                     //   589,824 sh
  unsigned short* Wk_f    = Wq_f + 589824;                      //   589,824 sh
  unsigned short* headW_f = Wk_f + 589824;                      // 1,179,648 sh
  unsigned short* tailW_f = headW_f + 1179648;                  // 1,179,648 sh
  unsigned short* hs16 = tailW_f + 1179648;                 // 1,695,744 sh (fp16 row-major)
  unsigned short* ts16 = hs16 + 1695744;                    // 1,695,744 sh
  unsigned short* Wbf  = ts16 + 1695744;                    // 6,881,280 sh (fp16)
  float* partial = ws;   // 24*2208*97 = 5,140,224 f, overlaps dead prefix region

  k_prep   <<<3168, 256, 0, stream>>>(bilW, Wbf, seq, seqf, W_q, Wq_f, W_k, Wk_f,
                                      headW, headW_f, tailW, tailW_f);
  k_ent_att<<<Bc*Ec*Hc, 256, 0, stream>>>(att, mpos, seq, ent_att, ment, ment_bf);
  k_ht_att <<<4*560, 256, 0, stream>>>(ent_att, hts, htbf);
  {
    FJob jrs = { htbf, nullptr, seqf, nullptr, rs_bf, Pc, 35,
                 (size_t)HT_ABS, (size_t)(48*32*512), Pc };
    k_fgemm<32,0,2><<<dim3(5,12,4), 256, 0, stream>>>(jrs, jrs, 5);
  }
  {
    FJob jq = { rs_bf,   nullptr, Wq_f, nullptr, q_c,   Rc,       138, 0, 0, 0 };
    FJob jk = { ment_bf, nullptr, Wk_f, nullptr, kment, Bc*Ec*Mc,  24, 0, 0, 0 };
    k_fgemm<24,0,0><<<dim3(21,12), 256, 0, stream>>>(jq, jk, 18);
  }
  k_pool   <<<Rc, 256, 0, stream>>>(kment, ment, q_c, hts, h_bf, t_bf);
  {
    FJob jh = { h_bf, rs_bf, headW_f, headb, hs16, Rc, 138, 0, 0, 0 };
    FJob jt = { t_bf, rs_bf, tailW_f, tailb, ts16, Rc, 138, 0, 0, 0 };
    k_fgemm<24,24,1><<<dim3(36,12), 256, 0, stream>>>(jh, jt, 18);
  }
  k_bilinear_mfma<<<18*KSPL, 256, 0, stream>>>(hs16, ts16, Wbf, partial);
  k_reduce <<<(Rc*NLc+255)/256, 256, 0, stream>>>(partial, bilb, out);
}